// Round 6
// baseline (288.412 us; speedup 1.0000x reference)
//
#include <hip/hip_runtime.h>

// GCN encoder: out = prelu( (Dinv A_hat Dinv X) W^T + b ).
// R13: producer-consumer fusion of gather+GEMM in ONE dispatch.
// Grid = NGB gather blocks + NRB GEMM blocks. Gather block g signals
// done[g>>3] (release/agent). GEMM block rb spins (acquire) for its 8
// producers, staging its first W tile before the wait. Deadlock-safe for
// any dispatch order: 391 waiters << ~1024 co-resident slots.
// Occupancy fixes vs R9/R11 fusion: Bs is 64 rows (17.4 KB -> LDS never
// caps blocks/CU) and As staging deleted (each A element is used by one
// lane once -> LDS round-trip was pure overhead; read ag direct from L2).

#define F_IN 128
#define H_OUT 512

typedef __bf16 bf16x8 __attribute__((ext_vector_type(8)));
typedef float  f32x4  __attribute__((ext_vector_type(4)));

// Multi-role prep: blocks [0,NWB) cast W->bf16; [NWB,NWB+NXB) cast x->bf16;
// rest count in-degrees, recording each edge's intra-segment position.
__global__ __launch_bounds__(256) void prep_kernel(const float* __restrict__ W,
                                                   __bf16* __restrict__ Wb, int nw8,
                                                   const float* __restrict__ x,
                                                   __bf16* __restrict__ xs, int nx8,
                                                   const int* __restrict__ col,
                                                   unsigned* __restrict__ deg,
                                                   unsigned* __restrict__ pos, int E,
                                                   int NWB, int NXB) {
    const int b = blockIdx.x, t = threadIdx.x;
    if (b < NWB) {
        int i = b * 256 + t;
        if (i >= nw8) return;
        float4 a0 = ((const float4*)W)[i * 2];
        float4 a1 = ((const float4*)W)[i * 2 + 1];
        bf16x8 v;
        v[0] = (__bf16)a0.x; v[1] = (__bf16)a0.y; v[2] = (__bf16)a0.z; v[3] = (__bf16)a0.w;
        v[4] = (__bf16)a1.x; v[5] = (__bf16)a1.y; v[6] = (__bf16)a1.z; v[7] = (__bf16)a1.w;
        ((bf16x8*)Wb)[i] = v;
    } else if (b < NWB + NXB) {
        int i = (b - NWB) * 256 + t;
        if (i >= nx8) return;
        float4 a0 = ((const float4*)x)[i * 2];
        float4 a1 = ((const float4*)x)[i * 2 + 1];
        bf16x8 v;
        v[0] = (__bf16)a0.x; v[1] = (__bf16)a0.y; v[2] = (__bf16)a0.z; v[3] = (__bf16)a0.w;
        v[4] = (__bf16)a1.x; v[5] = (__bf16)a1.y; v[6] = (__bf16)a1.z; v[7] = (__bf16)a1.w;
        ((bf16x8*)xs)[i] = v;
    } else {
        int e = (b - NWB - NXB) * 256 + t;
        if (e < E) pos[e] = atomicAdd(&deg[col[e]], 1u);  // returns old = position
    }
}

// Order-free CSR segment assignment: wave-scan of 8-ALIGNED deg, one atomic
// per wave. Aligned segment starts -> adj+rowptr[i] is 32B-aligned, enabling
// int4 adj loads in the gather. Gaps hold garbage; gather predicates them off.
__global__ __launch_bounds__(256) void assign_kernel(const unsigned* __restrict__ deg,
                                                     unsigned* __restrict__ total,
                                                     int* __restrict__ rowptr,
                                                     float* __restrict__ dinv, int n) {
    const int i = blockIdx.x * 256 + threadIdx.x;
    const int lane = threadIdx.x & 63;
    unsigned d = (i < n) ? deg[i] : 0u;
    unsigned da = (d + 7u) & ~7u;           // 8-aligned segment size
    unsigned x = da;
    #pragma unroll
    for (int o = 1; o < 64; o <<= 1) {
        unsigned y = __shfl_up(x, (unsigned)o, 64);
        if (lane >= o) x += y;
    }
    unsigned tot = __shfl(x, 63, 64);       // wave total (aligned)
    unsigned wb = 0;
    if (lane == 63) wb = atomicAdd(total, tot);
    wb = __shfl(wb, 63, 64);                // wave base
    if (i < n) {
        rowptr[i] = (int)(wb + x - da);     // aligned segment start
        dinv[i]   = rsqrtf((float)(d + 1u));  // +1 self-loop
    }
}

// Atomic-free fill: adj[rowptr[col[e]] + pos[e]] = row[e].
__global__ __launch_bounds__(256) void fill_csr_kernel(const int* __restrict__ row,
                                                       const int* __restrict__ col,
                                                       const unsigned* __restrict__ pos,
                                                       const int* __restrict__ rowptr,
                                                       int* __restrict__ adj, int E) {
    int e = blockIdx.x * 256 + threadIdx.x;
    if (e >= E) return;
    adj[rowptr[col[e]] + (int)pos[e]] = row[e];
}

// Fused producer-consumer gather + GEMM.
// bid < NGB:  gather role — 16 nodes, predicated 8-wide edge loop, write ag,
//             then signal done[bid>>3] (release, agent scope).
// bid >= NGB: GEMM role — stage first 64-row W tile, spin-wait (acquire) on
//             done[rb], hoist A-frags direct from L2-resident ag, loop 8
//             64-col tiles of W through Bs, epilogue bias+PReLU, NT stores.
__global__ __launch_bounds__(256, 4) void gather_gemm_kernel(
        const int* __restrict__ rowptr, const unsigned* __restrict__ deg,
        const int* __restrict__ adj, const __bf16* __restrict__ xs,
        const float* __restrict__ dinv, __bf16* __restrict__ ag,
        const __bf16* __restrict__ Wb, const float* __restrict__ bias,
        const float* __restrict__ alpha, unsigned* __restrict__ done,
        float* __restrict__ out, int N, int NGB) {
    __shared__ __bf16 Bs[64][136];  // 17.4 KB (+8 pad, 2-way reads = free)

    const int bid = blockIdx.x;
    const int t   = threadIdx.x;

    if (bid < NGB) {
        // ---------------- gather role ----------------
        const int node = bid * 16 + (t >> 4);
        const int li   = t & 15;
        if (node < N) {
            const bf16x8* xs8 = (const bf16x8*)xs;  // 16 chunks per row
            const float dvn = dinv[node];
            bf16x8 sv = xs8[(size_t)node * 16 + li];
            float acc[8];
            #pragma unroll
            for (int q = 0; q < 8; ++q) acc[q] = dvn * (float)sv[q];

            const int s = rowptr[node];
            const int e = s + (int)deg[node];
            for (int j = s; j < e; j += 8) {
                int4 ra  = *(const int4*)(adj + j);      // 32B-aligned segment
                int4 rb4 = *(const int4*)(adj + j + 4);
                int rr[8];
                rr[0] = ra.x;  rr[1] = ra.y;  rr[2] = ra.z;  rr[3] = ra.w;
                rr[4] = rb4.x; rr[5] = rb4.y; rr[6] = rb4.z; rr[7] = rb4.w;
                float wgt[8]; bf16x8 v[8];
                #pragma unroll
                for (int u = 0; u < 8; ++u) {
                    const bool ok = (j + u) < e;
                    const int r = ok ? rr[u] : node;   // dead slot -> self (cached)
                    wgt[u] = ok ? dinv[r] : 0.0f;
                    v[u]   = xs8[(size_t)r * 16 + li];
                }
                #pragma unroll
                for (int u = 0; u < 8; ++u) {
                    #pragma unroll
                    for (int q = 0; q < 8; ++q) acc[q] += wgt[u] * (float)v[u][q];
                }
            }

            bf16x8 o;
            #pragma unroll
            for (int q = 0; q < 8; ++q) o[q] = (__bf16)(acc[q] * dvn);
            ((bf16x8*)ag)[(size_t)node * 16 + li] = o;
        }
        // Signal: syncthreads drains vmcnt (stores at L2); release-RMW at
        // agent scope writes back/orders for cross-XCD consumers.
        __syncthreads();
        if (t == 0)
            __hip_atomic_fetch_add(&done[bid >> 3], 1u,
                                   __ATOMIC_RELEASE, __HIP_MEMORY_SCOPE_AGENT);
        return;
    }

    // ---------------- GEMM role ----------------
    const int rbi = bid - NGB;
    const int rb  = rbi * 128;

    // Stage Bs tile 0 (independent of gather) before waiting.
    #pragma unroll
    for (int i = 0; i < 4; ++i) {
        int c  = i * 256 + t;
        int r  = c >> 4;
        int k8 = (c & 15) * 8;
        *(bf16x8*)&Bs[r][k8] = *(const bf16x8*)(Wb + (size_t)r * F_IN + k8);
    }

    // Wait for the 8 gather blocks covering rows rb..rb+127.
    const int nprod = NGB - rbi * 8;
    const int expct = nprod < 8 ? nprod : 8;
    if (t == 0) {
        while ((int)__hip_atomic_load(&done[rbi], __ATOMIC_ACQUIRE,
                                      __HIP_MEMORY_SCOPE_AGENT) < expct)
            __builtin_amdgcn_s_sleep(2);
    }
    __syncthreads();  // Bs staged + flag observed (acquire invalidated L2)

    const int w    = t >> 6;
    const int lane = t & 63;
    const int lrow = lane & 15;
    const int lkc  = lane >> 4;      // k-chunk (8 elems) within 32
    const int rloc = (lane >> 4) * 4;

    // A-fragments straight from L2/L3-resident ag (each element used once).
    const bf16x8* ag8 = (const bf16x8*)ag;
    int r0 = rb + w * 32 + lrow;      if (r0 > N - 1) r0 = N - 1;
    int r1 = rb + w * 32 + 16 + lrow; if (r1 > N - 1) r1 = N - 1;
    bf16x8 af0[4], af1[4];
    #pragma unroll
    for (int ks = 0; ks < 4; ++ks) {
        af0[ks] = ag8[(size_t)r0 * 16 + ks * 4 + lkc];
        af1[ks] = ag8[(size_t)r1 * 16 + ks * 4 + lkc];
    }

    #pragma unroll
    for (int ct = 0; ct < 8; ++ct) {
        const int cb = ct * 64;
        if (ct) {
            __syncthreads();
            #pragma unroll
            for (int i = 0; i < 4; ++i) {
                int c  = i * 256 + t;
                int r  = c >> 4;
                int k8 = (c & 15) * 8;
                *(bf16x8*)&Bs[r][k8] =
                    *(const bf16x8*)(Wb + (size_t)(cb + r) * F_IN + k8);
            }
            __syncthreads();
        }

        f32x4 acc[2][4] = {};
        #pragma unroll
        for (int ks = 0; ks < 4; ++ks) {
            const int k0 = ks * 32 + lkc * 8;
            #pragma unroll
            for (int tn = 0; tn < 4; ++tn) {
                bf16x8 bfr = *(const bf16x8*)&Bs[tn * 16 + lrow][k0];
                acc[0][tn] = __builtin_amdgcn_mfma_f32_16x16x32_bf16(af0[ks], bfr, acc[0][tn], 0, 0, 0);
                acc[1][tn] = __builtin_amdgcn_mfma_f32_16x16x32_bf16(af1[ks], bfr, acc[1][tn], 0, 0, 0);
            }
        }

        // Epilogue: bias + PReLU; C/D layout col=lane&15, row=(lane>>4)*4+reg.
        float bb[4], aa[4];
        #pragma unroll
        for (int tn = 0; tn < 4; ++tn) {
            int n = cb + tn * 16 + lrow;
            bb[tn] = bias[n];
            aa[tn] = alpha[n];
        }
        #pragma unroll
        for (int tm = 0; tm < 2; ++tm) {
            #pragma unroll
            for (int r = 0; r < 4; ++r) {
                int m = rb + w * 32 + tm * 16 + rloc + r;
                if (m >= N) continue;
                #pragma unroll
                for (int tn = 0; tn < 4; ++tn) {
                    int n = cb + tn * 16 + lrow;
                    float v = acc[tm][tn][r] + bb[tn];
                    v = v > 0.f ? v : aa[tn] * v;
                    __builtin_nontemporal_store(v, &out[(size_t)m * H_OUT + n]);
                }
            }
        }
    }
}

extern "C" void kernel_launch(void* const* d_in, const int* in_sizes, int n_in,
                              void* d_out, int out_size, void* d_ws, size_t ws_size,
                              hipStream_t stream) {
    const float* x     = (const float*)d_in[0];
    const int*   ei    = (const int*)d_in[1];
    const float* W     = (const float*)d_in[2];
    const float* b     = (const float*)d_in[3];
    const float* alpha = (const float*)d_in[4];
    float*       out   = (float*)d_out;

    const int N = in_sizes[0] / F_IN;
    const int E = in_sizes[1] / 2;
    const int* row = ei;         // source
    const int* col = ei + E;     // target

    const int NGB = (N + 15) / 16;    // gather blocks
    const int NRB = (N + 127) / 128;  // GEMM row-blocks

    // Workspace layout (64B-aligned sections).
    char* wsb = (char*)d_ws;
    size_t off = 0;
    __bf16* xs = (__bf16*)(wsb + off);  off += (size_t)N * F_IN * 2;     off = (off + 63) & ~(size_t)63;
    __bf16* ag = (__bf16*)(wsb + off);  off += (size_t)N * F_IN * 2;     off = (off + 63) & ~(size_t)63;
    __bf16* Wb = (__bf16*)(wsb + off);  off += (size_t)H_OUT * F_IN * 2; off = (off + 63) & ~(size_t)63;
    unsigned* deg  = (unsigned*)(wsb + off);  off += (size_t)(N + 1) * 4;  // deg[N] = scan total
    unsigned* done = (unsigned*)(wsb + off);  off += (size_t)NRB * 4;      // per-row-block flags
    float*    dinv   = (float*)(wsb + off);   off += (size_t)N * 4;
    int*      rowptr = (int*)(wsb + off);     off += (size_t)N * 4;
    off = (off + 63) & ~(size_t)63;
    unsigned* pos = (unsigned*)(wsb + off);   off += (size_t)E * 4;
    off = (off + 63) & ~(size_t)63;
    int* adj = (int*)(wsb + off);   // aligned CSR: up to E + 8N ints
    unsigned* total = deg + N;

    const int nw8 = H_OUT * F_IN / 8;
    const int nx8 = N * F_IN / 8;
    const int NWB = (nw8 + 255) / 256;
    const int NXB = (nx8 + 255) / 256;
    const int NEB = (E + 255) / 256;

    // 1. zero deg + scan total + done flags (contiguous)
    hipMemsetAsync(deg, 0, (size_t)(N + 1 + NRB) * 4, stream);
    // 2. cast W, cast x, count deg + record positions
    prep_kernel<<<NWB + NXB + NEB, 256, 0, stream>>>(W, Wb, nw8, x, xs, nx8,
                                                     col, deg, pos, E, NWB, NXB);
    // 3. aligned segment assignment + dinv
    assign_kernel<<<(N + 255) / 256, 256, 0, stream>>>(deg, total, rowptr, dinv, N);
    // 4. atomic-free fill
    fill_csr_kernel<<<(E + 255) / 256, 256, 0, stream>>>(row, col, pos, rowptr, adj, E);
    // 5. fused producer-consumer gather + GEMM (one dispatch)
    gather_gemm_kernel<<<NGB + NRB, 256, 0, stream>>>(
        rowptr, deg, adj, xs, dinv, ag, Wb, b, alpha, done, out, N, NGB);
}

// Round 8
// 207.710 us; speedup vs baseline: 1.3885x; 1.3885x over previous
//
#include <hip/hip_runtime.h>

// GCN encoder: out = prelu( (Dinv A_hat Dinv X) W^T + b ).
// R15: R14 compile fix — __builtin_nontemporal_load needs a clang
// ext_vector_type pointer, not HIP's float4 struct. Loads go through f32x4.
// Structure = R12 (best, 209.5us): separate gather + one-pass GEMM,
// NT loads of read-once fp32 x/W in prep, NT stores of out in GEMM.

#define F_IN 128
#define H_OUT 512

typedef __bf16 bf16x8 __attribute__((ext_vector_type(8)));
typedef float  f32x4  __attribute__((ext_vector_type(4)));

// Multi-role prep: blocks [0,NWB) cast W->bf16; [NWB,NWB+NXB) cast x->bf16;
// rest count in-degrees, recording each edge's intra-segment position.
__global__ __launch_bounds__(256) void prep_kernel(const float* __restrict__ W,
                                                   __bf16* __restrict__ Wb, int nw8,
                                                   const float* __restrict__ x,
                                                   __bf16* __restrict__ xs, int nx8,
                                                   const int* __restrict__ col,
                                                   unsigned* __restrict__ deg,
                                                   unsigned* __restrict__ pos, int E,
                                                   int NWB, int NXB) {
    const int b = blockIdx.x, t = threadIdx.x;
    if (b < NWB) {
        int i = b * 256 + t;
        if (i >= nw8) return;
        f32x4 a0 = __builtin_nontemporal_load(&((const f32x4*)W)[i * 2]);
        f32x4 a1 = __builtin_nontemporal_load(&((const f32x4*)W)[i * 2 + 1]);
        bf16x8 v;
        v[0] = (__bf16)a0[0]; v[1] = (__bf16)a0[1]; v[2] = (__bf16)a0[2]; v[3] = (__bf16)a0[3];
        v[4] = (__bf16)a1[0]; v[5] = (__bf16)a1[1]; v[6] = (__bf16)a1[2]; v[7] = (__bf16)a1[3];
        ((bf16x8*)Wb)[i] = v;
    } else if (b < NWB + NXB) {
        int i = (b - NWB) * 256 + t;
        if (i >= nx8) return;
        f32x4 a0 = __builtin_nontemporal_load(&((const f32x4*)x)[i * 2]);
        f32x4 a1 = __builtin_nontemporal_load(&((const f32x4*)x)[i * 2 + 1]);
        bf16x8 v;
        v[0] = (__bf16)a0[0]; v[1] = (__bf16)a0[1]; v[2] = (__bf16)a0[2]; v[3] = (__bf16)a0[3];
        v[4] = (__bf16)a1[0]; v[5] = (__bf16)a1[1]; v[6] = (__bf16)a1[2]; v[7] = (__bf16)a1[3];
        ((bf16x8*)xs)[i] = v;
    } else {
        int e = (b - NWB - NXB) * 256 + t;
        if (e < E) pos[e] = atomicAdd(&deg[col[e]], 1u);  // returns old = position
    }
}

// Order-free CSR segment assignment: wave-scan of 8-ALIGNED deg, one atomic
// per wave. Aligned segment starts -> adj+rowptr[i] is 32B-aligned, enabling
// int4 adj loads in the gather. Gaps hold garbage; gather predicates them off.
__global__ __launch_bounds__(256) void assign_kernel(const unsigned* __restrict__ deg,
                                                     unsigned* __restrict__ total,
                                                     int* __restrict__ rowptr,
                                                     float* __restrict__ dinv, int n) {
    const int i = blockIdx.x * 256 + threadIdx.x;
    const int lane = threadIdx.x & 63;
    unsigned d = (i < n) ? deg[i] : 0u;
    unsigned da = (d + 7u) & ~7u;           // 8-aligned segment size
    unsigned x = da;
    #pragma unroll
    for (int o = 1; o < 64; o <<= 1) {
        unsigned y = __shfl_up(x, (unsigned)o, 64);
        if (lane >= o) x += y;
    }
    unsigned tot = __shfl(x, 63, 64);       // wave total (aligned)
    unsigned wb = 0;
    if (lane == 63) wb = atomicAdd(total, tot);
    wb = __shfl(wb, 63, 64);                // wave base
    if (i < n) {
        rowptr[i] = (int)(wb + x - da);     // aligned segment start
        dinv[i]   = rsqrtf((float)(d + 1u));  // +1 self-loop
    }
}

// Atomic-free fill: adj[rowptr[col[e]] + pos[e]] = row[e].
__global__ __launch_bounds__(256) void fill_csr_kernel(const int* __restrict__ row,
                                                       const int* __restrict__ col,
                                                       const unsigned* __restrict__ pos,
                                                       const int* __restrict__ rowptr,
                                                       int* __restrict__ adj, int E) {
    int e = blockIdx.x * 256 + threadIdx.x;
    if (e >= E) return;
    adj[rowptr[col[e]] + (int)pos[e]] = row[e];
}

// Aggregate: ag[c,:] = bf16( dinv[c] * ( dinv[c]*xs[c,:] + sum_r dinv[r]*xs[r,:] ) ).
// 16 lanes per node (16B/lane = 256B row), 4 nodes per wave.
// Single fully-predicated 8-wide loop: dead slots read the self row (L1-hot)
// with weight 0, so EVERY edge group keeps 8 gathers in flight.
__global__ __launch_bounds__(256) void gather_agg_kernel(const int* __restrict__ rowptr,
                                                         const unsigned* __restrict__ deg,
                                                         const int* __restrict__ adj,
                                                         const __bf16* __restrict__ xs,
                                                         const float* __restrict__ dinv,
                                                         __bf16* __restrict__ ag, int N) {
    const int t = threadIdx.x;
    const int node = blockIdx.x * 16 + (t >> 4);
    if (node >= N) return;
    const int li = t & 15;

    const bf16x8* xs8 = (const bf16x8*)xs;  // 16 chunks per row
    const float dvn = dinv[node];
    bf16x8 sv = xs8[(size_t)node * 16 + li];
    float acc[8];
    #pragma unroll
    for (int q = 0; q < 8; ++q) acc[q] = dvn * (float)sv[q];

    const int s = rowptr[node];
    const int e = s + (int)deg[node];
    for (int j = s; j < e; j += 8) {
        int4 ra  = *(const int4*)(adj + j);      // 32B-aligned segment
        int4 rb4 = *(const int4*)(adj + j + 4);
        int rr[8];
        rr[0] = ra.x;  rr[1] = ra.y;  rr[2] = ra.z;  rr[3] = ra.w;
        rr[4] = rb4.x; rr[5] = rb4.y; rr[6] = rb4.z; rr[7] = rb4.w;
        float wgt[8]; bf16x8 v[8];
        #pragma unroll
        for (int u = 0; u < 8; ++u) {
            const bool ok = (j + u) < e;
            const int r = ok ? rr[u] : node;   // dead slot -> self (cached)
            wgt[u] = ok ? dinv[r] : 0.0f;
            v[u]   = xs8[(size_t)r * 16 + li];
        }
        #pragma unroll
        for (int u = 0; u < 8; ++u) {
            #pragma unroll
            for (int q = 0; q < 8; ++q) acc[q] += wgt[u] * (float)v[u][q];
        }
    }

    bf16x8 o;
    #pragma unroll
    for (int q = 0; q < 8; ++q) o[q] = (__bf16)(acc[q] * dvn);
    ((bf16x8*)ag)[(size_t)node * 16 + li] = o;
}

// bf16 MFMA GEMM, one pass: out[m,:] = prelu( ag[m,:] @ W^T + b ).
// 128-row block, loops all 4 col-tiles of W through one Bs buffer.
// ag read ONCE (12.8 MB), A-frags hoisted, nontemporal fp32 stores.
__global__ __launch_bounds__(256) void gemm_mfma_kernel(const __bf16* __restrict__ ag,
                                                        const __bf16* __restrict__ Wb,
                                                        const float* __restrict__ bias,
                                                        const float* __restrict__ alpha,
                                                        float* __restrict__ out, int N) {
    __shared__ __bf16 As[128][136];  // +8 pad
    __shared__ __bf16 Bs[128][136];

    const int rb = blockIdx.x * 128;
    const int t  = threadIdx.x;

    // Stage As (whole K=128) and Bs for col-tile 0.
    #pragma unroll
    for (int i = 0; i < 8; ++i) {
        int c  = i * 256 + t;
        int r  = c >> 4;
        int k8 = (c & 15) * 8;
        bf16x8 v;
        #pragma unroll
        for (int j = 0; j < 8; ++j) v[j] = (__bf16)0.0f;
        if (rb + r < N) v = *(const bf16x8*)(ag + (size_t)(rb + r) * F_IN + k8);
        *(bf16x8*)&As[r][k8] = v;
    }
    #pragma unroll
    for (int i = 0; i < 8; ++i) {
        int c  = i * 256 + t;
        int r  = c >> 4;
        int k8 = (c & 15) * 8;
        *(bf16x8*)&Bs[r][k8] = *(const bf16x8*)(Wb + (size_t)r * F_IN + k8);
    }
    __syncthreads();

    const int w    = t >> 6;
    const int lane = t & 63;
    const int lrow = lane & 15;
    const int lk   = (lane >> 4) * 8;
    const int rloc = (lane >> 4) * 4;

    // Hoist A fragments: each As element read from LDS exactly once.
    bf16x8 af0[4], af1[4];
    #pragma unroll
    for (int ks = 0; ks < 4; ++ks) {
        const int k0 = ks * 32 + lk;
        af0[ks] = *(const bf16x8*)&As[w * 32 + lrow][k0];
        af1[ks] = *(const bf16x8*)&As[w * 32 + 16 + lrow][k0];
    }

    #pragma unroll
    for (int ct = 0; ct < 4; ++ct) {
        const int cb = ct * 128;

        f32x4 acc[2][8] = {};
        #pragma unroll
        for (int ks = 0; ks < 4; ++ks) {
            const int k0 = ks * 32 + lk;
            #pragma unroll
            for (int tn = 0; tn < 8; ++tn) {
                bf16x8 bfr = *(const bf16x8*)&Bs[tn * 16 + lrow][k0];
                acc[0][tn] = __builtin_amdgcn_mfma_f32_16x16x32_bf16(af0[ks], bfr, acc[0][tn], 0, 0, 0);
                acc[1][tn] = __builtin_amdgcn_mfma_f32_16x16x32_bf16(af1[ks], bfr, acc[1][tn], 0, 0, 0);
            }
        }

        // Epilogue: bias + PReLU; C/D layout col=lane&15, row=(lane>>4)*4+reg.
        // Nontemporal: out is write-once, never re-read -> bypass L2 allocation.
        float bb[8], aa[8];
        #pragma unroll
        for (int tn = 0; tn < 8; ++tn) {
            int n = cb + tn * 16 + lrow;
            bb[tn] = bias[n];
            aa[tn] = alpha[n];
        }
        #pragma unroll
        for (int tm = 0; tm < 2; ++tm) {
            #pragma unroll
            for (int r = 0; r < 4; ++r) {
                int m = rb + w * 32 + tm * 16 + rloc + r;
                if (m >= N) continue;
                #pragma unroll
                for (int tn = 0; tn < 8; ++tn) {
                    int n = cb + tn * 16 + lrow;
                    float v = acc[tm][tn][r] + bb[tn];
                    v = v > 0.f ? v : aa[tn] * v;
                    __builtin_nontemporal_store(v, &out[(size_t)m * H_OUT + n]);
                }
            }
        }

        // Swap in next col-tile of W (Bs reads above are done after this sync).
        if (ct < 3) {
            __syncthreads();
            #pragma unroll
            for (int i = 0; i < 8; ++i) {
                int c  = i * 256 + t;
                int r  = c >> 4;
                int k8 = (c & 15) * 8;
                *(bf16x8*)&Bs[r][k8] =
                    *(const bf16x8*)(Wb + (size_t)(cb + 128 + r) * F_IN + k8);
            }
            __syncthreads();
        }
    }
}

extern "C" void kernel_launch(void* const* d_in, const int* in_sizes, int n_in,
                              void* d_out, int out_size, void* d_ws, size_t ws_size,
                              hipStream_t stream) {
    const float* x     = (const float*)d_in[0];
    const int*   ei    = (const int*)d_in[1];
    const float* W     = (const float*)d_in[2];
    const float* b     = (const float*)d_in[3];
    const float* alpha = (const float*)d_in[4];
    float*       out   = (float*)d_out;

    const int N = in_sizes[0] / F_IN;
    const int E = in_sizes[1] / 2;
    const int* row = ei;         // source
    const int* col = ei + E;     // target

    // Workspace layout (64B-aligned sections).
    char* wsb = (char*)d_ws;
    size_t off = 0;
    __bf16* xs = (__bf16*)(wsb + off);  off += (size_t)N * F_IN * 2;     off = (off + 63) & ~(size_t)63;
    __bf16* ag = (__bf16*)(wsb + off);  off += (size_t)N * F_IN * 2;     off = (off + 63) & ~(size_t)63;
    __bf16* Wb = (__bf16*)(wsb + off);  off += (size_t)H_OUT * F_IN * 2; off = (off + 63) & ~(size_t)63;
    unsigned* deg    = (unsigned*)(wsb + off);  off += (size_t)(N + 1) * 4;  // deg[N] = scan total
    float*    dinv   = (float*)(wsb + off);     off += (size_t)N * 4;
    int*      rowptr = (int*)(wsb + off);       off += (size_t)N * 4;
    off = (off + 63) & ~(size_t)63;
    unsigned* pos = (unsigned*)(wsb + off);     off += (size_t)E * 4;
    off = (off + 63) & ~(size_t)63;
    int* adj = (int*)(wsb + off);   // aligned CSR: up to E + 8N ints
    unsigned* total = deg + N;

    const int nw8 = H_OUT * F_IN / 8;
    const int nx8 = N * F_IN / 8;
    const int NWB = (nw8 + 255) / 256;
    const int NXB = (nx8 + 255) / 256;
    const int NEB = (E + 255) / 256;

    // 1. zero deg + scan total
    hipMemsetAsync(deg, 0, (size_t)(N + 1) * 4, stream);
    // 2. cast W, cast x, count deg + record positions
    prep_kernel<<<NWB + NXB + NEB, 256, 0, stream>>>(W, Wb, nw8, x, xs, nx8,
                                                     col, deg, pos, E, NWB, NXB);
    // 3. aligned segment assignment + dinv
    assign_kernel<<<(N + 255) / 256, 256, 0, stream>>>(deg, total, rowptr, dinv, N);
    // 4. atomic-free fill
    fill_csr_kernel<<<(E + 255) / 256, 256, 0, stream>>>(row, col, pos, rowptr, adj, E);
    // 5. weighted gather-aggregate (predicated 8-wide, full occupancy)
    gather_agg_kernel<<<(N + 15) / 16, 256, 0, stream>>>(rowptr, deg, adj, xs, dinv, ag, N);
    // 6. one-pass MFMA GEMM + bias + PReLU (nontemporal stores)
    gemm_mfma_kernel<<<(N + 127) / 128, 256, 0, stream>>>(ag, Wb, b, alpha, out, N);
}